// Round 6
// baseline (243.552 us; speedup 1.0000x reference)
//
#include <hip/hip_runtime.h>
#include <cstdint>
#include <cstddef>

#define HID 1024
#define NH 16
#define HD 64
#define SEQ 2048
#define BATCH 2

typedef __attribute__((ext_vector_type(8))) short bf16x8;
typedef __attribute__((ext_vector_type(4))) float f32x4;

__device__ __forceinline__ unsigned short f2bf(float f){
  unsigned u = __builtin_bit_cast(unsigned, f);
  u += 0x7fffu + ((u >> 16) & 1u);
  return (unsigned short)(u >> 16);
}

// async global->LDS, 16B per lane. LDS dest is wave-uniform base; HW adds lane*16B.
__device__ __forceinline__ void gll(const unsigned short* g, unsigned short* l){
  __builtin_amdgcn_global_load_lds(
      (const __attribute__((address_space(1))) unsigned int*)(g),
      (__attribute__((address_space(3))) unsigned int*)(l),
      16, 0, 0);
}

// split-k unit tables: 40 units per bh, each <= 8 k-tiles of 64 keys
__device__ __constant__ int UQB[40] = {15,15,15,15, 14,14,14,14, 13,13,13,13, 12,12,12,12,
                                       11,11,11, 10,10,10, 9,9,9, 8,8,8,
                                       7,7, 6,6, 5,5, 4,4, 3, 2, 1, 0};
__device__ __constant__ int UCH[40] = {0,1,2,3, 0,1,2,3, 0,1,2,3, 0,1,2,3,
                                       0,1,2, 0,1,2, 0,1,2, 0,1,2,
                                       0,1, 0,1, 0,1, 0,1, 0, 0, 0, 0};

// ---------------- fp32 -> bf16 conversion of x and the 4 weights ----------------
__global__ __launch_bounds__(256) void cvt_all(
    const float* __restrict__ x,  const float* __restrict__ wq,
    const float* __restrict__ wk, const float* __restrict__ wv,
    const float* __restrict__ wo,
    unsigned short* __restrict__ xb,  unsigned short* __restrict__ wqb,
    unsigned short* __restrict__ wkb, unsigned short* __restrict__ wvb,
    unsigned short* __restrict__ wob)
{
  const size_t NX = (size_t)BATCH*SEQ*HID;   // 4M
  const size_t NW = (size_t)HID*HID;         // 1M
  size_t i = ((size_t)blockIdx.x*256 + threadIdx.x)*4;
  const float* src; unsigned short* dst; size_t off;
  if (i < NX) { src = x; dst = xb; off = i; }
  else {
    size_t j = i - NX; int w = (int)(j >> 20); off = j & (NW-1);
    if      (w==0){ src=wq; dst=wqb; }
    else if (w==1){ src=wk; dst=wkb; }
    else if (w==2){ src=wv; dst=wvb; }
    else          { src=wo; dst=wob; }
  }
  float4 v = *(const float4*)(src+off);
  uint2 p;
  p.x = (unsigned)f2bf(v.x) | ((unsigned)f2bf(v.y)<<16);
  p.y = (unsigned)f2bf(v.z) | ((unsigned)f2bf(v.w)<<16);
  *(uint2*)(dst+off) = p;
}

// -------- fused QKV GEMM, BK=64, head-major bf16 out --------
// Q output pre-scaled by 0.125*log2(e).
__global__ __launch_bounds__(256) void gemm_qkv(
    const unsigned short* __restrict__ A,
    const unsigned short* __restrict__ Bq,
    const unsigned short* __restrict__ Bk,
    const unsigned short* __restrict__ Bv,
    unsigned short* __restrict__ Qh,
    unsigned short* __restrict__ Kh,
    unsigned short* __restrict__ Vh)
{
  __shared__ unsigned short As[8192];  // halves [128][32] at 0, 4096
  __shared__ unsigned short Bs[8192];
  const int tid = threadIdx.x;
  const int w = tid >> 6, lane = tid & 63, l15 = lane & 15, quad = lane >> 4;
  const int wm = (w >> 1)*64, wn = (w & 1)*64;
  const int bm = blockIdx.y*128;
  const int which = blockIdx.x >> 3;           // 0=Q 1=K 2=V
  const int bn = (blockIdx.x & 7)*128;
  const unsigned short* B = which==0 ? Bq : (which==1 ? Bk : Bv);
  unsigned short* C       = which==0 ? Qh : (which==1 ? Kh : Vh);
  const float cscale      = which==0 ? 0.18033688011112042f : 1.0f;
  const int lrow = lane >> 2, lcol = (lane & 3)*8;

  f32x4 acc[4][4] = {};
  for (int kb=0; kb<16; ++kb){
    __syncthreads();
    #pragma unroll
    for (int p=0;p<4;p++){
      int c = p*4 + w;                         // 0..15: half h=c>>3, rowblk rb=c&7
      int h = c >> 3, rb = c & 7;
      gll(&A[(size_t)(bm + rb*16 + lrow)*HID + kb*64 + h*32 + lcol], &As[h*4096 + rb*512]);
      gll(&B[(size_t)(bn + rb*16 + lrow)*HID + kb*64 + h*32 + lcol], &Bs[h*4096 + rb*512]);
    }
    __syncthreads();
    #pragma unroll
    for (int kc=0;kc<2;kc++){
      bf16x8 af[4], bfr[4];
      #pragma unroll
      for (int i=0;i<4;i++) af[i]  = *(const bf16x8*)(&As[kc*4096 + (wm + i*16 + l15)*32 + quad*8]);
      #pragma unroll
      for (int j=0;j<4;j++) bfr[j] = *(const bf16x8*)(&Bs[kc*4096 + (wn + j*16 + l15)*32 + quad*8]);
      #pragma unroll
      for (int i=0;i<4;i++)
        #pragma unroll
        for (int j=0;j<4;j++)
          acc[i][j] = __builtin_amdgcn_mfma_f32_16x16x32_bf16(af[i], bfr[j], acc[i][j], 0,0,0);
    }
  }
  #pragma unroll
  for (int i=0;i<4;i++)
    #pragma unroll
    for (int j=0;j<4;j++)
      #pragma unroll
      for (int r=0;r<4;r++){
        int m = bm + wm + i*16 + quad*4 + r;
        int n = bn + wn + j*16 + l15;
        int b = m >> 11, t = m & (SEQ-1), h = n >> 6, d = n & (HD-1);
        C[(((size_t)(b*NH + h))*SEQ + t)*HD + d] = f2bf(acc[i][j][r]*cscale);
      }
}

// -------- output projection, BK=64, 128x64 tiles: fp32 out --------
__global__ __launch_bounds__(256) void gemm_out(
    const unsigned short* __restrict__ A,
    const unsigned short* __restrict__ B,
    float* __restrict__ C)
{
  __shared__ unsigned short As[8192];  // halves [128][32]
  __shared__ unsigned short Bs[4096];  // halves [64][32]
  const int tid = threadIdx.x;
  const int w = tid >> 6, lane = tid & 63, l15 = lane & 15, quad = lane >> 4;
  const int wm = (w >> 1)*64, wn = (w & 1)*32;
  const int bm = blockIdx.y*128, bn = blockIdx.x*64;
  const int lrow = lane >> 2, lcol = (lane & 3)*8;

  f32x4 acc[4][2] = {};
  for (int kb=0; kb<16; ++kb){
    __syncthreads();
    #pragma unroll
    for (int p=0;p<4;p++){
      int c = p*4 + w;
      int h = c >> 3, rb = c & 7;
      gll(&A[(size_t)(bm + rb*16 + lrow)*HID + kb*64 + h*32 + lcol], &As[h*4096 + rb*512]);
    }
    #pragma unroll
    for (int p=0;p<2;p++){
      int c = p*4 + w;                          // 0..7
      int h = c >> 2, rb = c & 3;
      gll(&B[(size_t)(bn + rb*16 + lrow)*HID + kb*64 + h*32 + lcol], &Bs[h*2048 + rb*512]);
    }
    __syncthreads();
    #pragma unroll
    for (int kc=0;kc<2;kc++){
      bf16x8 af[4], bfr[2];
      #pragma unroll
      for (int i=0;i<4;i++) af[i]  = *(const bf16x8*)(&As[kc*4096 + (wm + i*16 + l15)*32 + quad*8]);
      #pragma unroll
      for (int j=0;j<2;j++) bfr[j] = *(const bf16x8*)(&Bs[kc*2048 + (wn + j*16 + l15)*32 + quad*8]);
      #pragma unroll
      for (int i=0;i<4;i++)
        #pragma unroll
        for (int j=0;j<2;j++)
          acc[i][j] = __builtin_amdgcn_mfma_f32_16x16x32_bf16(af[i], bfr[j], acc[i][j], 0,0,0);
    }
  }
  #pragma unroll
  for (int i=0;i<4;i++)
    #pragma unroll
    for (int j=0;j<2;j++)
      #pragma unroll
      for (int r=0;r<4;r++){
        int m = bm + wm + i*16 + quad*4 + r;
        int n = bn + wn + j*16 + l15;
        C[(size_t)m*HID + n] = acc[i][j][r];
      }
}

// -------- transpose V per head: [bh][t][d] -> [bh][d][t] --------
__global__ __launch_bounds__(256) void vtrans(
    const unsigned short* __restrict__ Vh, unsigned short* __restrict__ VhT)
{
  __shared__ unsigned short t[64*66];
  const int bh = blockIdx.y, tb = blockIdx.x;
  const int tid = threadIdx.x;
  const unsigned short* src = Vh + ((size_t)bh*SEQ + tb*64)*HD;
  #pragma unroll
  for (int i=0;i<2;i++){
    int c = i*256 + tid; int r = c >> 3, c8 = (c & 7)*8;
    unsigned short tmp[8];
    *(uint4*)tmp = *(const uint4*)(&src[r*HD + c8]);
    #pragma unroll
    for (int j=0;j<8;j++) t[(c8+j)*66 + r] = tmp[j];
  }
  __syncthreads();
  unsigned short* dst = VhT + (size_t)bh*HD*SEQ + tb*64;
  #pragma unroll
  for (int i=0;i<2;i++){
    int c = i*256 + tid; int d = c >> 3, t8 = (c & 7)*8;
    uint4 v; unsigned short* pv = (unsigned short*)&v;
    #pragma unroll
    for (int j=0;j<8;j++) pv[j] = t[d*66 + t8 + j];
    *(uint4*)(&dst[(size_t)d*SEQ + t8]) = v;
  }
}

// -------- split-k flash attention: 512 thr, <=8 k-tiles/block, atomic combine ----
// Qh pre-scaled by 0.125*log2e, Kh head-major [bh][t][d]; VhT [bh][d][t].
// Partials: OunnA (bh<16) / OunnB (bh>=16) fp32 [bh][t][64]; L fp32 [bh*2048+t].
__global__ __launch_bounds__(512) void attn(
    const unsigned short* __restrict__ Qh,
    const unsigned short* __restrict__ Kh,
    const unsigned short* __restrict__ VhT,
    float* __restrict__ OunnA, float* __restrict__ OunnB,
    float* __restrict__ L)
{
  __shared__ unsigned short Ks[4096];   // halves [64][32] at 0,2048
  __shared__ unsigned short Vt[4096];   // key-halves [64][32] of V^T[d][k]
  __shared__ unsigned short Ps[9728];   // per-wave [16][76]

  const int unit = blockIdx.x;          // 0..39
  const int bh   = blockIdx.y;          // 0..31
  const int qb   = UQB[unit];
  const int ch   = UCH[unit];
  const int tid = threadIdx.x;
  const int w = tid >> 6, lane = tid & 63, l15 = lane & 15, quad = lane >> 4;
  const int lrow = lane >> 2, lcol = (lane & 3)*8;

  const size_t base = (size_t)bh * SEQ * HD;
  const unsigned short* Qg = Qh + base + (size_t)qb*128*HD;
  const unsigned short* VTg = VhT + base;   // [d][t]
  unsigned short* Psw = &Ps[w*1216];
  float* Ounn = (bh < 16) ? (OunnA + (size_t)bh*SEQ*HD)
                          : (OunnB + (size_t)(bh-16)*SEQ*HD);

  const int mrow = w*16;                 // this wave's rows within the 128-tile
  // q-frags straight from global (one scattered-16B load per kc; L2-resident)
  bf16x8 qfrag[2];
  #pragma unroll
  for (int kc=0;kc<2;kc++)
    qfrag[kc] = *(const bf16x8*)(&Qg[(size_t)(mrow + l15)*HD + kc*32 + quad*8]);

  float l_lane[4] = {};
  f32x4 oacc[4] = {};

  const int kb_lo = ch*8;
  const int kb_hi = min(kb_lo + 8, 2*qb + 2);
  for (int kb=kb_lo; kb<kb_hi; ++kb){
    __syncthreads();
    const unsigned short* Kg = Kh + base + (size_t)kb*64*HD;
    // waves 0-3 stage K (8 chunks), waves 4-7 stage V^T (8 chunks)
    {
      int c2 = (w & 3)*2;
      if (w < 4){
        #pragma unroll
        for (int p=0;p<2;p++){
          int cc = c2 + p;               // 0..7: half=cc>>2, rowblk=cc&3
          gll(&Kg[(size_t)((cc&3)*16 + lrow)*HD + (cc>>2)*32 + lcol], &Ks[(cc>>2)*2048 + (cc&3)*512]);
        }
      } else {
        #pragma unroll
        for (int p=0;p<2;p++){
          int cc = c2 + p;
          gll(&VTg[(size_t)((cc&3)*16 + lrow)*SEQ + kb*64 + (cc>>2)*32 + lcol], &Vt[(cc>>2)*2048 + (cc&3)*512]);
        }
      }
    }
    __syncthreads();

    if (kb*64 > qb*128 + mrow + 15) continue;      // fully-masked for this wave

    f32x4 s[4] = {};
    #pragma unroll
    for (int cb=0;cb<4;cb++)
      #pragma unroll
      for (int kc=0;kc<2;kc++){
        bf16x8 kfr = *(const bf16x8*)(&Ks[kc*2048 + (cb*16 + l15)*32 + quad*8]);
        s[cb] = __builtin_amdgcn_mfma_f32_16x16x32_bf16(qfrag[kc], kfr, s[cb], 0,0,0);
      }

    const bool need_mask = (kb*64 + 63 > qb*128 + mrow);
    // no-offset softmax: p = exp2(s'); the implicit 2^C cancels in O/l.
    #pragma unroll
    for (int cb=0;cb<4;cb++)
      #pragma unroll
      for (int r=0;r<4;r++){
        float sv = s[cb][r];
        if (need_mask){
          int qrow = qb*128 + mrow + quad*4 + r;
          int kcol = kb*64 + cb*16 + l15;
          if (kcol > qrow) sv = -1e30f;
        }
        s[cb][r] = exp2f(sv);
      }
    #pragma unroll
    for (int r=0;r<4;r++)
      l_lane[r] += (s[0][r] + s[1][r]) + (s[2][r] + s[3][r]);

    // P: C-layout regs -> wave-private LDS [16][76] -> A-layout frags
    #pragma unroll
    for (int cb=0;cb<4;cb++)
      #pragma unroll
      for (int r=0;r<4;r++)
        Psw[(quad*4 + r)*76 + cb*16 + l15] = f2bf(s[cb][r]);
    bf16x8 pa[2];
    #pragma unroll
    for (int kc=0;kc<2;kc++)
      pa[kc] = *(const bf16x8*)(&Psw[l15*76 + kc*32 + quad*8]);
    #pragma unroll
    for (int db=0;db<4;db++)
      #pragma unroll
      for (int kc=0;kc<2;kc++){
        bf16x8 vfr = *(const bf16x8*)(&Vt[kc*2048 + (db*16 + l15)*32 + quad*8]);
        oacc[db] = __builtin_amdgcn_mfma_f32_16x16x32_bf16(pa[kc], vfr, oacc[db], 0,0,0);
      }
  }

  // epilogue: reduce l over the 16-lane row group, then atomic combine
  #pragma unroll
  for (int r=0;r<4;r++){
    float l = l_lane[r];
    l += __shfl_xor(l, 1); l += __shfl_xor(l, 2);
    l += __shfl_xor(l, 4); l += __shfl_xor(l, 8);
    l_lane[r] = l;
  }
  const int row0 = qb*128 + mrow;
  if (l15 == 0){
    #pragma unroll
    for (int r=0;r<4;r++)
      atomicAdd(&L[(size_t)bh*SEQ + row0 + quad*4 + r], l_lane[r]);
  }
  #pragma unroll
  for (int db=0;db<4;db++)
    #pragma unroll
    for (int r=0;r<4;r++)
      atomicAdd(&Ounn[(size_t)(row0 + quad*4 + r)*HD + db*16 + l15], oacc[db][r]);
}

// -------- normalize: Ao bf16 [b*SEQ+t][HID] = Ounn / L --------
__global__ __launch_bounds__(256) void normalize(
    const float* __restrict__ OunnA, const float* __restrict__ OunnB,
    const float* __restrict__ L, unsigned short* __restrict__ Ao)
{
  int idx = blockIdx.x*256 + threadIdx.x;   // one fp32 element each, 4M total
  int d = idx & 63; int ri = idx >> 6;
  int bh = ri >> 11; int t = ri & (SEQ-1);
  const float* O = (bh < 16) ? (OunnA + (size_t)ri*HD)
                             : (OunnB + (size_t)(ri - 16*SEQ)*HD);
  float inv = 1.0f / L[ri];
  int b = bh >> 4, h = bh & (NH-1);
  Ao[((size_t)(b*SEQ + t))*HID + h*HD + d] = f2bf(O[d] * inv);
}

extern "C" void kernel_launch(void* const* d_in, const int* in_sizes, int n_in,
                              void* d_out, int out_size, void* d_ws, size_t ws_size,
                              hipStream_t stream)
{
  const float* x  = (const float*)d_in[0];
  const float* Wq = (const float*)d_in[1];
  const float* Wk = (const float*)d_in[2];
  const float* Wv = (const float*)d_in[3];
  const float* Wo = (const float*)d_in[4];

  // ws (ushort elems): xb 4M | wqb..wob 1M each | Qh 4M | Kh 4M | Vh 4M | VhT 4M = 48MB
  // region reuse: xb -> OunnA (fp32, bh<16), wqb -> L, Vh -> OunnB, Qh -> Ao.
  unsigned short* xb  = (unsigned short*)d_ws;
  unsigned short* wqb = xb  + (size_t)4*1024*1024;
  unsigned short* wkb = wqb + (size_t)1024*1024;
  unsigned short* wvb = wkb + (size_t)1024*1024;
  unsigned short* wob = wvb + (size_t)1024*1024;
  unsigned short* Qh  = wob + (size_t)1024*1024;
  unsigned short* Kh  = Qh  + (size_t)4*1024*1024;
  unsigned short* Vh  = Kh  + (size_t)4*1024*1024;
  unsigned short* VhT = Vh  + (size_t)4*1024*1024;

  float* OunnA = (float*)xb;    // 2M floats = 8MB (bh 0..15)
  float* OunnB = (float*)Vh;    // 2M floats = 8MB (bh 16..31)
  float* L     = (float*)wqb;   // 64K floats = 256KB
  unsigned short* Ao = Qh;      // Q dead after attn

  cvt_all<<<8192, 256, 0, stream>>>(x, Wq, Wk, Wv, Wo, xb, wqb, wkb, wvb, wob);

  gemm_qkv<<<dim3(24, 32), 256, 0, stream>>>(xb, wqb, wkb, wvb, Qh, Kh, Vh);

  vtrans<<<dim3(SEQ/64, BATCH*NH), 256, 0, stream>>>(Vh, VhT);

  // zero the atomic-combine buffers (xb/wqb dead after gemm_qkv, Vh dead after vtrans)
  hipMemsetAsync(OunnA, 0, (size_t)16*SEQ*HD*sizeof(float), stream);
  hipMemsetAsync(OunnB, 0, (size_t)16*SEQ*HD*sizeof(float), stream);
  hipMemsetAsync(L,     0, (size_t)BATCH*NH*SEQ*sizeof(float), stream);

  attn<<<dim3(40, BATCH*NH), 512, 0, stream>>>(Qh, Kh, VhT, OunnA, OunnB, L);

  normalize<<<(BATCH*NH*SEQ*HD)/256, 256, 0, stream>>>(OunnA, OunnB, L, Ao);

  gemm_out<<<dim3(16, 32), 256, 0, stream>>>(Ao, wob, (float*)d_out);
}